// Round 1
// baseline (300.406 us; speedup 1.0000x reference)
//
#include <hip/hip_runtime.h>
#include <hip/hip_bf16.h>
#include <stdint.h>

#define B_     8
#define TT     1024
#define DIM_   2048
#define S_     512
#define H_     16
#define DH     64
#define HID    1024

typedef _Float16 half8 __attribute__((ext_vector_type(8)));
typedef _Float16 half4v __attribute__((ext_vector_type(4)));
typedef float f32x4 __attribute__((ext_vector_type(4)));

__device__ __forceinline__ void gload_lds16(const void* g, void* l) {
  __builtin_amdgcn_global_load_lds(
      (__attribute__((address_space(1))) unsigned int*)(uintptr_t)g,
      (__attribute__((address_space(3))) unsigned int*)l, 16, 0, 0);
}

// ---------------- LayerNorm + cast to fp16 ----------------
__global__ __launch_bounds__(256) void ln_cast(
    const float* __restrict__ x, const float* __restrict__ gamma,
    const float* __restrict__ beta, _Float16* __restrict__ xn)
{
  const int row = blockIdx.x;
  const int tid = threadIdx.x;
  const float* xr = x + (size_t)row * DIM_;
  float4 a = ((const float4*)xr)[tid * 2];
  float4 b = ((const float4*)xr)[tid * 2 + 1];
  float s1 = a.x + a.y + a.z + a.w + b.x + b.y + b.z + b.w;
  float s2 = a.x*a.x + a.y*a.y + a.z*a.z + a.w*a.w
           + b.x*b.x + b.y*b.y + b.z*b.z + b.w*b.w;
  #pragma unroll
  for (int d = 1; d < 64; d <<= 1) {
    s1 += __shfl_xor(s1, d, 64);
    s2 += __shfl_xor(s2, d, 64);
  }
  __shared__ float red[8];
  const int w = tid >> 6, lane = tid & 63;
  if (lane == 0) { red[w] = s1; red[4 + w] = s2; }
  __syncthreads();
  s1 = red[0] + red[1] + red[2] + red[3];
  s2 = red[4] + red[5] + red[6] + red[7];
  const float mu  = s1 * (1.0f / DIM_);
  const float var = s2 * (1.0f / DIM_) - mu * mu;
  const float rs  = rsqrtf(var + 1e-5f);
  float4 g0 = ((const float4*)gamma)[tid * 2];
  float4 g1 = ((const float4*)gamma)[tid * 2 + 1];
  float4 e0 = ((const float4*)beta)[tid * 2];
  float4 e1 = ((const float4*)beta)[tid * 2 + 1];
  half8 o;
  o[0] = (_Float16)((a.x - mu) * rs * g0.x + e0.x);
  o[1] = (_Float16)((a.y - mu) * rs * g0.y + e0.y);
  o[2] = (_Float16)((a.z - mu) * rs * g0.z + e0.z);
  o[3] = (_Float16)((a.w - mu) * rs * g0.w + e0.w);
  o[4] = (_Float16)((b.x - mu) * rs * g1.x + e1.x);
  o[5] = (_Float16)((b.y - mu) * rs * g1.y + e1.y);
  o[6] = (_Float16)((b.z - mu) * rs * g1.z + e1.z);
  o[7] = (_Float16)((b.w - mu) * rs * g1.w + e1.w);
  *(half8*)(xn + (size_t)row * DIM_ + tid * 8) = o;
}

// ---------------- elementwise f32 -> f16 cast ----------------
__global__ __launch_bounds__(256) void cast_f16(
    const float* __restrict__ in, _Float16* __restrict__ out, int n4)
{
  int i = blockIdx.x * 256 + threadIdx.x;
  if (i >= n4) return;
  float4 v = ((const float4*)in)[i];
  half4v o;
  o[0] = (_Float16)v.x; o[1] = (_Float16)v.y;
  o[2] = (_Float16)v.z; o[3] = (_Float16)v.w;
  ((half4v*)out)[i] = o;
}

// ---------------- transpose + cast: in[R][C] f32 -> out[C][R] f16 ----------------
__global__ void transpose_cast(const float* __restrict__ in,
                               _Float16* __restrict__ out, int R, int C)
{
  __shared__ float t[32][33];
  const int c0 = blockIdx.x * 32, r0 = blockIdx.y * 32;
  const int tx = threadIdx.x, ty = threadIdx.y;
  #pragma unroll
  for (int i = 0; i < 32; i += 8)
    t[ty + i][tx] = in[(size_t)(r0 + ty + i) * C + c0 + tx];
  __syncthreads();
  #pragma unroll
  for (int i = 0; i < 32; i += 8)
    out[(size_t)(c0 + ty + i) * R + r0 + tx] = (_Float16)t[tx][ty + i];
}

// ---------------- V^T builder: kv[B*S][2048] cols 1024+ -> vt[B][H][DH][S] ----------------
__global__ void build_vt(const _Float16* __restrict__ kv, _Float16* __restrict__ vt)
{
  __shared__ _Float16 t[64][65];
  const int s0 = blockIdx.x * 64;
  const int h = blockIdx.y, b = blockIdx.z;
  const int tx = threadIdx.x, ty = threadIdx.y;
  const _Float16* src = kv + (size_t)(b * S_) * 2048 + HID + h * DH;
  #pragma unroll
  for (int i = 0; i < 64; i += 8)
    t[ty + i][tx] = src[(size_t)(s0 + ty + i) * 2048 + tx];
  __syncthreads();
  _Float16* dst = vt + (size_t)((b * H_ + h) * DH) * S_;
  #pragma unroll
  for (int i = 0; i < 64; i += 8)
    dst[(size_t)(ty + i) * S_ + s0 + tx] = t[tx][ty + i];
}

// ---------------- fp16 GEMM: C[M][N] = A[M][K] @ BT[N][K]^T ----------------
// 128x128 tile, BK=32, 4 waves (2x2), each wave 64x64 via 4x4 16x16x32 mfma.
template<typename OutT>
__global__ __launch_bounds__(256) void gemm_f16(
    const _Float16* __restrict__ A, const _Float16* __restrict__ BT,
    OutT* __restrict__ C, int M, int N, int K)
{
  __shared__ __align__(16) _Float16 sA[2][128 * 32];
  __shared__ __align__(16) _Float16 sB[2][128 * 32];
  const int tid = threadIdx.x;
  const int lane = tid & 63, w = tid >> 6;
  const int l15 = lane & 15, lhi = lane >> 4;
  const int wr = w >> 1, wc = w & 1;
  const int m0 = blockIdx.y * 128, n0 = blockIdx.x * 128;

  f32x4 acc[4][4] = {};

  const int rowA0 = tid >> 2,        cb0 = (tid & 3) * 8;         // chunks 0..255
  const int rowA1 = (256 + tid) >> 2, cb1 = (tid & 3) * 8;        // chunks 256..511

  auto stage = [&](const _Float16* __restrict__ G, _Float16* sbuf, int base, int k0) {
    gload_lds16(G + (size_t)(base + rowA0) * K + k0 + cb0, &sbuf[(w * 64) * 8]);
    gload_lds16(G + (size_t)(base + rowA1) * K + k0 + cb1, &sbuf[(256 + w * 64) * 8]);
  };

  stage(A,  sA[0], m0, 0);
  stage(BT, sB[0], n0, 0);
  __syncthreads();
  int cur = 0;
  for (int k0 = 0; k0 < K; k0 += 32) {
    const int nk = k0 + 32;
    if (nk < K) { stage(A, sA[cur ^ 1], m0, nk); stage(BT, sB[cur ^ 1], n0, nk); }
    half8 af[4], bf[4];
    #pragma unroll
    for (int m = 0; m < 4; ++m)
      af[m] = *(const half8*)&sA[cur][(wr * 64 + m * 16 + l15) * 32 + lhi * 8];
    #pragma unroll
    for (int n = 0; n < 4; ++n)
      bf[n] = *(const half8*)&sB[cur][(wc * 64 + n * 16 + l15) * 32 + lhi * 8];
    #pragma unroll
    for (int m = 0; m < 4; ++m)
      #pragma unroll
      for (int n = 0; n < 4; ++n)
        acc[m][n] = __builtin_amdgcn_mfma_f32_16x16x32_f16(af[m], bf[n], acc[m][n], 0, 0, 0);
    __syncthreads();
    cur ^= 1;
  }
  #pragma unroll
  for (int m = 0; m < 4; ++m) {
    const int row = m0 + wr * 64 + m * 16 + lhi * 4;
    #pragma unroll
    for (int n = 0; n < 4; ++n) {
      const int col = n0 + wc * 64 + n * 16 + l15;
      #pragma unroll
      for (int r = 0; r < 4; ++r)
        C[(size_t)(row + r) * N + col] = (OutT)acc[m][n][r];
    }
  }
}

// ---------------- fused attention: per (b,h,64-row q-tile) ----------------
// wave w handles 16 q rows. scores [16][512] in regs -> softmax/8 -> P in
// XOR-swizzled LDS -> P@V via vt (V^T) global fragments.
__global__ __launch_bounds__(256) void attn_kernel(
    const _Float16* __restrict__ q, const _Float16* __restrict__ kv,
    const _Float16* __restrict__ vt, _Float16* __restrict__ ao)
{
  __shared__ __align__(16) _Float16 P[4][16][512];   // 64 KiB
  const int tid = threadIdx.x;
  const int lane = tid & 63, w = tid >> 6;
  const int l15 = lane & 15, lhi = lane >> 4;
  const int tb = blockIdx.x, h = blockIdx.y, b = blockIdx.z;
  const int t0 = tb * 64 + w * 16;

  const _Float16* qp = q + (size_t)(b * TT + t0 + l15) * HID + h * DH + lhi * 8;
  half8 aq0 = *(const half8*)qp;
  half8 aq1 = *(const half8*)(qp + 32);

  f32x4 accs[32] = {};
  const _Float16* kb = kv + (size_t)(b * S_) * 2048 + h * DH + lhi * 8;
  #pragma unroll
  for (int n = 0; n < 32; ++n) {
    const _Float16* kp = kb + (size_t)(n * 16 + l15) * 2048;
    accs[n] = __builtin_amdgcn_mfma_f32_16x16x32_f16(aq0, *(const half8*)kp,        accs[n], 0, 0, 0);
    accs[n] = __builtin_amdgcn_mfma_f32_16x16x32_f16(aq1, *(const half8*)(kp + 32), accs[n], 0, 0, 0);
  }
  // softmax over s (row = lhi*4+r, col = n*16+l15); reduce across 16 lanes of group lhi
  #pragma unroll
  for (int r = 0; r < 4; ++r) {
    float mx = accs[0][r];
    #pragma unroll
    for (int n = 1; n < 32; ++n) mx = fmaxf(mx, accs[n][r]);
    mx = fmaxf(mx, __shfl_xor(mx, 1, 64));
    mx = fmaxf(mx, __shfl_xor(mx, 2, 64));
    mx = fmaxf(mx, __shfl_xor(mx, 4, 64));
    mx = fmaxf(mx, __shfl_xor(mx, 8, 64));
    float sm = 0.f;
    #pragma unroll
    for (int n = 0; n < 32; ++n) { float e = __expf(accs[n][r] - mx); accs[n][r] = e; sm += e; }
    sm += __shfl_xor(sm, 1, 64);
    sm += __shfl_xor(sm, 2, 64);
    sm += __shfl_xor(sm, 4, 64);
    sm += __shfl_xor(sm, 8, 64);
    const float inv = 1.0f / (sm * 8.0f);   // softmax then /sqrt(DH)
    const int rw = lhi * 4 + r;
    const int sw = (rw & 7) << 3;
    #pragma unroll
    for (int n = 0; n < 32; ++n)
      P[w][rw][(n * 16 + l15) ^ sw] = (_Float16)(accs[n][r] * inv);
  }
  __syncthreads();
  // PV: out[16][64] += P[16][512] @ V[512][64]  (B-operand from vt = V^T)
  f32x4 acco[4] = {};
  const _Float16* vb = vt + (size_t)((b * H_ + h) * DH) * S_;
  const int swr = (l15 & 7) << 3;
  #pragma unroll
  for (int ks = 0; ks < 16; ++ks) {
    half8 ap = *(const half8*)&P[w][l15][(ks * 32 + lhi * 8) ^ swr];
    #pragma unroll
    for (int n = 0; n < 4; ++n) {
      const _Float16* vp = vb + (size_t)(n * 16 + l15) * S_ + ks * 32 + lhi * 8;
      acco[n] = __builtin_amdgcn_mfma_f32_16x16x32_f16(ap, *(const half8*)vp, acco[n], 0, 0, 0);
    }
  }
  _Float16* ob = ao + (size_t)(b * TT + t0 + lhi * 4) * HID + h * DH;
  #pragma unroll
  for (int n = 0; n < 4; ++n)
    #pragma unroll
    for (int r = 0; r < 4; ++r)
      ob[(size_t)r * HID + n * 16 + l15] = (_Float16)acco[n][r];
}

extern "C" void kernel_launch(void* const* d_in, const int* in_sizes, int n_in,
                              void* d_out, int out_size, void* d_ws, size_t ws_size,
                              hipStream_t stream) {
  const float* x     = (const float*)d_in[0];
  const float* media = (const float*)d_in[1];
  // d_in[2] media_locations: unused (reference discards the mask)
  const float* Wq    = (const float*)d_in[3];
  const float* Wkv   = (const float*)d_in[4];
  const float* Wo    = (const float*)d_in[5];
  const float* gamma = (const float*)d_in[6];
  const float* beta  = (const float*)d_in[7];
  float* out = (float*)d_out;

  char* ws = (char*)d_ws;
  _Float16* xn     = (_Float16*)(ws);                    // 8192x2048 (32MB)
  _Float16* qh     = (_Float16*)(ws + 33554432);         // 8192x1024 (16MB)
  _Float16* kvh    = (_Float16*)(ws + 50331648);         // 4096x2048 (16MB)
  _Float16* aoh    = (_Float16*)(ws + 67108864);         // 8192x1024 (16MB)
  _Float16* vth    = (_Float16*)(ws + 83886080);         // 8x16x64x512 (8MB)
  _Float16* mediah = (_Float16*)(ws + 92274688);         // 4096x1024 (8MB)
  _Float16* wqT    = (_Float16*)(ws + 100663296);        // 1024x2048 (4MB)
  _Float16* wkvT   = (_Float16*)(ws + 104857600);        // 2048x1024 (4MB)
  _Float16* woT    = (_Float16*)(ws + 109051904);        // 2048x1024 (4MB)

  ln_cast<<<dim3(8192), dim3(256), 0, stream>>>(x, gamma, beta, xn);
  transpose_cast<<<dim3(1024/32, 2048/32), dim3(32, 8), 0, stream>>>(Wq,  wqT,  2048, 1024);
  transpose_cast<<<dim3(2048/32, 1024/32), dim3(32, 8), 0, stream>>>(Wkv, wkvT, 1024, 2048);
  transpose_cast<<<dim3(2048/32, 1024/32), dim3(32, 8), 0, stream>>>(Wo,  woT,  1024, 2048);
  cast_f16<<<dim3(4096), dim3(256), 0, stream>>>(media, mediah, 4194304 / 4);

  gemm_f16<_Float16><<<dim3(1024/128, 8192/128), dim3(256), 0, stream>>>(xn, wqT, qh, 8192, 1024, 2048);
  gemm_f16<_Float16><<<dim3(2048/128, 4096/128), dim3(256), 0, stream>>>(mediah, wkvT, kvh, 4096, 2048, 1024);
  build_vt<<<dim3(8, 16, 8), dim3(64, 8), 0, stream>>>(kvh, vth);
  attn_kernel<<<dim3(16, 16, 8), dim3(256), 0, stream>>>(qh, kvh, vth, aoh);
  gemm_f16<float><<<dim3(2048/128, 8192/128), dim3(256), 0, stream>>>(aoh, woT, out, 8192, 2048, 1024);
}

// Round 3
// 287.563 us; speedup vs baseline: 1.0447x; 1.0447x over previous
//
#include <hip/hip_runtime.h>
#include <hip/hip_bf16.h>
#include <stdint.h>

#define B_     8
#define TT     1024
#define DIM_   2048
#define S_     512
#define H_     16
#define DH     64
#define HID    1024

typedef _Float16 half8 __attribute__((ext_vector_type(8)));
typedef _Float16 half4v __attribute__((ext_vector_type(4)));
typedef float f32x4 __attribute__((ext_vector_type(4)));

__device__ __forceinline__ void gload_lds16(const void* g, void* l) {
  __builtin_amdgcn_global_load_lds(
      (__attribute__((address_space(1))) unsigned int*)(uintptr_t)g,
      (__attribute__((address_space(3))) unsigned int*)l, 16, 0, 0);
}

// ---------------- LayerNorm + cast to fp16 ----------------
__global__ __launch_bounds__(256) void ln_cast(
    const float* __restrict__ x, const float* __restrict__ gamma,
    const float* __restrict__ beta, _Float16* __restrict__ xn)
{
  const int row = blockIdx.x;
  const int tid = threadIdx.x;
  const float* xr = x + (size_t)row * DIM_;
  float4 a = ((const float4*)xr)[tid * 2];
  float4 b = ((const float4*)xr)[tid * 2 + 1];
  float s1 = a.x + a.y + a.z + a.w + b.x + b.y + b.z + b.w;
  float s2 = a.x*a.x + a.y*a.y + a.z*a.z + a.w*a.w
           + b.x*b.x + b.y*b.y + b.z*b.z + b.w*b.w;
  #pragma unroll
  for (int d = 1; d < 64; d <<= 1) {
    s1 += __shfl_xor(s1, d, 64);
    s2 += __shfl_xor(s2, d, 64);
  }
  __shared__ float red[8];
  const int w = tid >> 6, lane = tid & 63;
  if (lane == 0) { red[w] = s1; red[4 + w] = s2; }
  __syncthreads();
  s1 = red[0] + red[1] + red[2] + red[3];
  s2 = red[4] + red[5] + red[6] + red[7];
  const float mu  = s1 * (1.0f / DIM_);
  const float var = s2 * (1.0f / DIM_) - mu * mu;
  const float rs  = rsqrtf(var + 1e-5f);
  float4 g0 = ((const float4*)gamma)[tid * 2];
  float4 g1 = ((const float4*)gamma)[tid * 2 + 1];
  float4 e0 = ((const float4*)beta)[tid * 2];
  float4 e1 = ((const float4*)beta)[tid * 2 + 1];
  half8 o;
  o[0] = (_Float16)((a.x - mu) * rs * g0.x + e0.x);
  o[1] = (_Float16)((a.y - mu) * rs * g0.y + e0.y);
  o[2] = (_Float16)((a.z - mu) * rs * g0.z + e0.z);
  o[3] = (_Float16)((a.w - mu) * rs * g0.w + e0.w);
  o[4] = (_Float16)((b.x - mu) * rs * g1.x + e1.x);
  o[5] = (_Float16)((b.y - mu) * rs * g1.y + e1.y);
  o[6] = (_Float16)((b.z - mu) * rs * g1.z + e1.z);
  o[7] = (_Float16)((b.w - mu) * rs * g1.w + e1.w);
  *(half8*)(xn + (size_t)row * DIM_ + tid * 8) = o;
}

// ---------------- elementwise f32 -> f16 cast ----------------
__global__ __launch_bounds__(256) void cast_f16(
    const float* __restrict__ in, _Float16* __restrict__ out, int n4)
{
  int i = blockIdx.x * 256 + threadIdx.x;
  if (i >= n4) return;
  float4 v = ((const float4*)in)[i];
  half4v o;
  o[0] = (_Float16)v.x; o[1] = (_Float16)v.y;
  o[2] = (_Float16)v.z; o[3] = (_Float16)v.w;
  ((half4v*)out)[i] = o;
}

// ---------------- transpose + cast: in[R][C] f32 -> out[C][R] f16 ----------------
__global__ void transpose_cast(const float* __restrict__ in,
                               _Float16* __restrict__ out, int R, int C)
{
  __shared__ float t[32][33];
  const int c0 = blockIdx.x * 32, r0 = blockIdx.y * 32;
  const int tx = threadIdx.x, ty = threadIdx.y;
  #pragma unroll
  for (int i = 0; i < 32; i += 8)
    t[ty + i][tx] = in[(size_t)(r0 + ty + i) * C + c0 + tx];
  __syncthreads();
  #pragma unroll
  for (int i = 0; i < 32; i += 8)
    out[(size_t)(c0 + ty + i) * R + r0 + tx] = (_Float16)t[tx][ty + i];
}

// ---------------- V^T builder: kv[B*S][2048] cols 1024+ -> vt[B][H][DH][S] ----------------
__global__ void build_vt(const _Float16* __restrict__ kv, _Float16* __restrict__ vt)
{
  __shared__ _Float16 t[64][65];
  const int s0 = blockIdx.x * 64;
  const int h = blockIdx.y, b = blockIdx.z;
  const int tx = threadIdx.x, ty = threadIdx.y;
  const _Float16* src = kv + (size_t)(b * S_) * 2048 + HID + h * DH;
  #pragma unroll
  for (int i = 0; i < 64; i += 8)
    t[ty + i][tx] = src[(size_t)(s0 + ty + i) * 2048 + tx];
  __syncthreads();
  _Float16* dst = vt + (size_t)((b * H_ + h) * DH) * S_;
  #pragma unroll
  for (int i = 0; i < 64; i += 8)
    dst[(size_t)(ty + i) * S_ + s0 + tx] = t[tx][ty + i];
}

// ---------------- fp16 GEMM: C[M][N] = A[M][K] @ BT[N][K]^T ----------------
// 128x128 tile, BK=32, 4 waves (2x2), each wave 64x64 via 4x4 16x16x32 mfma.
template<typename OutT>
__global__ __launch_bounds__(256) void gemm_f16(
    const _Float16* __restrict__ A, const _Float16* __restrict__ BT,
    OutT* __restrict__ C, int M, int N, int K)
{
  __shared__ __align__(16) _Float16 sA[2][128 * 32];
  __shared__ __align__(16) _Float16 sB[2][128 * 32];
  const int tid = threadIdx.x;
  const int lane = tid & 63, w = tid >> 6;
  const int l15 = lane & 15, lhi = lane >> 4;
  const int wr = w >> 1, wc = w & 1;
  const int m0 = blockIdx.y * 128, n0 = blockIdx.x * 128;

  f32x4 acc[4][4] = {};

  const int rowA0 = tid >> 2,        cb0 = (tid & 3) * 8;         // chunks 0..255
  const int rowA1 = (256 + tid) >> 2, cb1 = (tid & 3) * 8;        // chunks 256..511

  auto stage = [&](const _Float16* __restrict__ G, _Float16* sbuf, int base, int k0) {
    gload_lds16(G + (size_t)(base + rowA0) * K + k0 + cb0, &sbuf[(w * 64) * 8]);
    gload_lds16(G + (size_t)(base + rowA1) * K + k0 + cb1, &sbuf[(256 + w * 64) * 8]);
  };

  stage(A,  sA[0], m0, 0);
  stage(BT, sB[0], n0, 0);
  __syncthreads();
  int cur = 0;
  for (int k0 = 0; k0 < K; k0 += 32) {
    const int nk = k0 + 32;
    if (nk < K) { stage(A, sA[cur ^ 1], m0, nk); stage(BT, sB[cur ^ 1], n0, nk); }
    half8 af[4], bf[4];
    #pragma unroll
    for (int m = 0; m < 4; ++m)
      af[m] = *(const half8*)&sA[cur][(wr * 64 + m * 16 + l15) * 32 + lhi * 8];
    #pragma unroll
    for (int n = 0; n < 4; ++n)
      bf[n] = *(const half8*)&sB[cur][(wc * 64 + n * 16 + l15) * 32 + lhi * 8];
    #pragma unroll
    for (int m = 0; m < 4; ++m)
      #pragma unroll
      for (int n = 0; n < 4; ++n)
        acc[m][n] = __builtin_amdgcn_mfma_f32_16x16x32_f16(af[m], bf[n], acc[m][n], 0, 0, 0);
    __syncthreads();
    cur ^= 1;
  }
  #pragma unroll
  for (int m = 0; m < 4; ++m) {
    const int row = m0 + wr * 64 + m * 16 + lhi * 4;
    #pragma unroll
    for (int n = 0; n < 4; ++n) {
      const int col = n0 + wc * 64 + n * 16 + l15;
      #pragma unroll
      for (int r = 0; r < 4; ++r)
        C[(size_t)(row + r) * N + col] = (OutT)acc[m][n][r];
    }
  }
}

// ---------------- fused attention v2: online softmax, S-chunks of 128 ----------------
// Grid (16,16,8), 4 waves/block, wave w owns 16 q rows. Per chunk: QK^T (8x2
// mfma) -> online max/sum update -> P chunk to per-wave swizzled LDS (16KB
// total, no __syncthreads) -> PV accumulate. Registers ~90 -> 4 waves/SIMD.
__global__ __launch_bounds__(256, 4) void attn_kernel(
    const _Float16* __restrict__ q, const _Float16* __restrict__ kv,
    const _Float16* __restrict__ vt, _Float16* __restrict__ ao)
{
  __shared__ __align__(16) _Float16 P[4][16][128];   // 16 KiB
  const int tid = threadIdx.x;
  const int lane = tid & 63, w = tid >> 6;
  const int l15 = lane & 15, lhi = lane >> 4;
  const int tb = blockIdx.x, h = blockIdx.y, b = blockIdx.z;
  const int t0 = tb * 64 + w * 16;

  const _Float16* qp = q + (size_t)(b * TT + t0 + l15) * HID + h * DH + lhi * 8;
  half8 aq0 = *(const half8*)qp;
  half8 aq1 = *(const half8*)(qp + 32);

  const _Float16* kb = kv + (size_t)(b * S_) * 2048 + h * DH + lhi * 8;
  const _Float16* vb = vt + (size_t)((b * H_ + h) * DH) * S_;
  const int swr = (l15 & 7) << 3;

  f32x4 acco[4] = {};
  float m_[4] = {-1e30f, -1e30f, -1e30f, -1e30f};
  float l_[4] = {0.f, 0.f, 0.f, 0.f};

  for (int c = 0; c < 4; ++c) {
    // --- QK^T for s in [c*128, c*128+128) ---
    f32x4 accs[8] = {};
    const _Float16* kc = kb + (size_t)(c * 128) * 2048;
    #pragma unroll
    for (int n = 0; n < 8; ++n) {
      const _Float16* kp = kc + (size_t)(n * 16 + l15) * 2048;
      accs[n] = __builtin_amdgcn_mfma_f32_16x16x32_f16(aq0, *(const half8*)kp,        accs[n], 0, 0, 0);
      accs[n] = __builtin_amdgcn_mfma_f32_16x16x32_f16(aq1, *(const half8*)(kp + 32), accs[n], 0, 0, 0);
    }
    // --- online softmax update (rows lhi*4+r, cols n*16+l15) ---
    #pragma unroll
    for (int r = 0; r < 4; ++r) {
      float mx = accs[0][r];
      #pragma unroll
      for (int n = 1; n < 8; ++n) mx = fmaxf(mx, accs[n][r]);
      mx = fmaxf(mx, __shfl_xor(mx, 1, 64));
      mx = fmaxf(mx, __shfl_xor(mx, 2, 64));
      mx = fmaxf(mx, __shfl_xor(mx, 4, 64));
      mx = fmaxf(mx, __shfl_xor(mx, 8, 64));
      const float mnew = fmaxf(m_[r], mx);
      const float scale = __expf(m_[r] - mnew);
      float sm = 0.f;
      #pragma unroll
      for (int n = 0; n < 8; ++n) {
        float e = __expf(accs[n][r] - mnew);
        accs[n][r] = e;
        sm += e;
      }
      sm += __shfl_xor(sm, 1, 64);
      sm += __shfl_xor(sm, 2, 64);
      sm += __shfl_xor(sm, 4, 64);
      sm += __shfl_xor(sm, 8, 64);
      l_[r] = l_[r] * scale + sm;
      m_[r] = mnew;
      #pragma unroll
      for (int n2 = 0; n2 < 4; ++n2) acco[n2][r] *= scale;
      const int rw = lhi * 4 + r;
      const int sw = (rw & 7) << 3;
      #pragma unroll
      for (int n = 0; n < 8; ++n)
        P[w][rw][(n * 16 + l15) ^ sw] = (_Float16)accs[n][r];
    }
    // --- PV partial: acco += P_chunk[16][128] @ V_chunk[128][64] ---
    // (per-wave private LDS region; compiler-inserted lgkmcnt orders it)
    #pragma unroll
    for (int ks = 0; ks < 4; ++ks) {
      half8 ap = *(const half8*)&P[w][l15][(ks * 32 + lhi * 8) ^ swr];
      #pragma unroll
      for (int n = 0; n < 4; ++n) {
        const _Float16* vp = vb + (size_t)(n * 16 + l15) * S_ + c * 128 + ks * 32 + lhi * 8;
        acco[n] = __builtin_amdgcn_mfma_f32_16x16x32_f16(ap, *(const half8*)vp, acco[n], 0, 0, 0);
      }
    }
  }
  // --- finalize: /(sum * SCALE) and store ---
  _Float16* ob = ao + (size_t)(b * TT + t0 + lhi * 4) * HID + h * DH;
  #pragma unroll
  for (int r = 0; r < 4; ++r) {
    const float inv = 1.0f / (l_[r] * 8.0f);
    #pragma unroll
    for (int n = 0; n < 4; ++n)
      ob[(size_t)r * HID + n * 16 + l15] = (_Float16)(acco[n][r] * inv);
  }
}

extern "C" void kernel_launch(void* const* d_in, const int* in_sizes, int n_in,
                              void* d_out, int out_size, void* d_ws, size_t ws_size,
                              hipStream_t stream) {
  const float* x     = (const float*)d_in[0];
  const float* media = (const float*)d_in[1];
  // d_in[2] media_locations: unused (reference discards the mask)
  const float* Wq    = (const float*)d_in[3];
  const float* Wkv   = (const float*)d_in[4];
  const float* Wo    = (const float*)d_in[5];
  const float* gamma = (const float*)d_in[6];
  const float* beta  = (const float*)d_in[7];
  float* out = (float*)d_out;

  char* ws = (char*)d_ws;
  _Float16* xn     = (_Float16*)(ws);                    // 8192x2048 (32MB)
  _Float16* qh     = (_Float16*)(ws + 33554432);         // 8192x1024 (16MB)
  _Float16* kvh    = (_Float16*)(ws + 50331648);         // 4096x2048 (16MB)
  _Float16* aoh    = (_Float16*)(ws + 67108864);         // 8192x1024 (16MB)
  _Float16* vth    = (_Float16*)(ws + 83886080);         // 8x16x64x512 (8MB)
  _Float16* mediah = (_Float16*)(ws + 92274688);         // 4096x1024 (8MB)
  _Float16* wqT    = (_Float16*)(ws + 100663296);        // 1024x2048 (4MB)
  _Float16* wkvT   = (_Float16*)(ws + 104857600);        // 2048x1024 (4MB)
  _Float16* woT    = (_Float16*)(ws + 109051904);        // 2048x1024 (4MB)

  ln_cast<<<dim3(8192), dim3(256), 0, stream>>>(x, gamma, beta, xn);
  transpose_cast<<<dim3(1024/32, 2048/32), dim3(32, 8), 0, stream>>>(Wq,  wqT,  2048, 1024);
  transpose_cast<<<dim3(2048/32, 1024/32), dim3(32, 8), 0, stream>>>(Wkv, wkvT, 1024, 2048);
  transpose_cast<<<dim3(2048/32, 1024/32), dim3(32, 8), 0, stream>>>(Wo,  woT,  1024, 2048);
  cast_f16<<<dim3(4096), dim3(256), 0, stream>>>(media, mediah, 4194304 / 4);

  gemm_f16<_Float16><<<dim3(1024/128, 8192/128), dim3(256), 0, stream>>>(xn, wqT, qh, 8192, 1024, 2048);
  gemm_f16<_Float16><<<dim3(2048/128, 4096/128), dim3(256), 0, stream>>>(mediah, wkvT, kvh, 4096, 2048, 1024);
  build_vt<<<dim3(8, 16, 8), dim3(64, 8), 0, stream>>>(kvh, vth);
  attn_kernel<<<dim3(16, 16, 8), dim3(256), 0, stream>>>(qh, kvh, vth, aoh);
  gemm_f16<float><<<dim3(2048/128, 8192/128), dim3(256), 0, stream>>>(aoh, woT, out, 8192, 2048, 1024);
}

// Round 4
// 225.714 us; speedup vs baseline: 1.3309x; 1.2740x over previous
//
#include <hip/hip_runtime.h>
#include <hip/hip_bf16.h>
#include <stdint.h>

#define B_     8
#define TT     1024
#define DIM_   2048
#define S_     512
#define H_     16
#define DH     64
#define HID    1024

typedef _Float16 half8 __attribute__((ext_vector_type(8)));
typedef _Float16 half4v __attribute__((ext_vector_type(4)));
typedef float f32x4 __attribute__((ext_vector_type(4)));

__device__ __forceinline__ void gload_lds16(const void* g, void* l) {
  __builtin_amdgcn_global_load_lds(
      (__attribute__((address_space(1))) unsigned int*)(uintptr_t)g,
      (__attribute__((address_space(3))) unsigned int*)l, 16, 0, 0);
}

// ---------------- LayerNorm + cast to fp16 ----------------
__global__ __launch_bounds__(256) void ln_cast(
    const float* __restrict__ x, const float* __restrict__ gamma,
    const float* __restrict__ beta, _Float16* __restrict__ xn)
{
  const int row = blockIdx.x;
  const int tid = threadIdx.x;
  const float* xr = x + (size_t)row * DIM_;
  float4 a = ((const float4*)xr)[tid * 2];
  float4 b = ((const float4*)xr)[tid * 2 + 1];
  float s1 = a.x + a.y + a.z + a.w + b.x + b.y + b.z + b.w;
  float s2 = a.x*a.x + a.y*a.y + a.z*a.z + a.w*a.w
           + b.x*b.x + b.y*b.y + b.z*b.z + b.w*b.w;
  #pragma unroll
  for (int d = 1; d < 64; d <<= 1) {
    s1 += __shfl_xor(s1, d, 64);
    s2 += __shfl_xor(s2, d, 64);
  }
  __shared__ float red[8];
  const int w = tid >> 6, lane = tid & 63;
  if (lane == 0) { red[w] = s1; red[4 + w] = s2; }
  __syncthreads();
  s1 = red[0] + red[1] + red[2] + red[3];
  s2 = red[4] + red[5] + red[6] + red[7];
  const float mu  = s1 * (1.0f / DIM_);
  const float var = s2 * (1.0f / DIM_) - mu * mu;
  const float rs  = rsqrtf(var + 1e-5f);
  float4 g0 = ((const float4*)gamma)[tid * 2];
  float4 g1 = ((const float4*)gamma)[tid * 2 + 1];
  float4 e0 = ((const float4*)beta)[tid * 2];
  float4 e1 = ((const float4*)beta)[tid * 2 + 1];
  half8 o;
  o[0] = (_Float16)((a.x - mu) * rs * g0.x + e0.x);
  o[1] = (_Float16)((a.y - mu) * rs * g0.y + e0.y);
  o[2] = (_Float16)((a.z - mu) * rs * g0.z + e0.z);
  o[3] = (_Float16)((a.w - mu) * rs * g0.w + e0.w);
  o[4] = (_Float16)((b.x - mu) * rs * g1.x + e1.x);
  o[5] = (_Float16)((b.y - mu) * rs * g1.y + e1.y);
  o[6] = (_Float16)((b.z - mu) * rs * g1.z + e1.z);
  o[7] = (_Float16)((b.w - mu) * rs * g1.w + e1.w);
  *(half8*)(xn + (size_t)row * DIM_ + tid * 8) = o;
}

// ---------------- elementwise f32 -> f16 cast ----------------
__global__ __launch_bounds__(256) void cast_f16(
    const float* __restrict__ in, _Float16* __restrict__ out, int n4)
{
  int i = blockIdx.x * 256 + threadIdx.x;
  if (i >= n4) return;
  float4 v = ((const float4*)in)[i];
  half4v o;
  o[0] = (_Float16)v.x; o[1] = (_Float16)v.y;
  o[2] = (_Float16)v.z; o[3] = (_Float16)v.w;
  ((half4v*)out)[i] = o;
}

// ---------------- transpose + cast: in[R][C] f32 -> out[C][R] f16 ----------------
__global__ void transpose_cast(const float* __restrict__ in,
                               _Float16* __restrict__ out, int R, int C)
{
  __shared__ float t[32][33];
  const int c0 = blockIdx.x * 32, r0 = blockIdx.y * 32;
  const int tx = threadIdx.x, ty = threadIdx.y;
  #pragma unroll
  for (int i = 0; i < 32; i += 8)
    t[ty + i][tx] = in[(size_t)(r0 + ty + i) * C + c0 + tx];
  __syncthreads();
  #pragma unroll
  for (int i = 0; i < 32; i += 8)
    out[(size_t)(c0 + ty + i) * R + r0 + tx] = (_Float16)t[tx][ty + i];
}

// ---------------- V^T builder: kv[B*S][2048] cols 1024+ -> vt[B][H][DH][S] ----------------
__global__ void build_vt(const _Float16* __restrict__ kv, _Float16* __restrict__ vt)
{
  __shared__ _Float16 t[64][65];
  const int s0 = blockIdx.x * 64;
  const int h = blockIdx.y, b = blockIdx.z;
  const int tx = threadIdx.x, ty = threadIdx.y;
  const _Float16* src = kv + (size_t)(b * S_) * 2048 + HID + h * DH;
  #pragma unroll
  for (int i = 0; i < 64; i += 8)
    t[ty + i][tx] = src[(size_t)(s0 + ty + i) * 2048 + tx];
  __syncthreads();
  _Float16* dst = vt + (size_t)((b * H_ + h) * DH) * S_;
  #pragma unroll
  for (int i = 0; i < 64; i += 8)
    dst[(size_t)(ty + i) * S_ + s0 + tx] = t[tx][ty + i];
}

// ---------------- fp16 GEMM: C[M][N] = A[M][K] @ BT[N][K]^T ----------------
template<typename OutT>
__global__ __launch_bounds__(256) void gemm_f16(
    const _Float16* __restrict__ A, const _Float16* __restrict__ BT,
    OutT* __restrict__ C, int M, int N, int K)
{
  __shared__ __align__(16) _Float16 sA[2][128 * 32];
  __shared__ __align__(16) _Float16 sB[2][128 * 32];
  const int tid = threadIdx.x;
  const int lane = tid & 63, w = tid >> 6;
  const int l15 = lane & 15, lhi = lane >> 4;
  const int wr = w >> 1, wc = w & 1;
  const int m0 = blockIdx.y * 128, n0 = blockIdx.x * 128;

  f32x4 acc[4][4] = {};

  const int rowA0 = tid >> 2,        cb0 = (tid & 3) * 8;
  const int rowA1 = (256 + tid) >> 2, cb1 = (tid & 3) * 8;

  auto stage = [&](const _Float16* __restrict__ G, _Float16* sbuf, int base, int k0) {
    gload_lds16(G + (size_t)(base + rowA0) * K + k0 + cb0, &sbuf[(w * 64) * 8]);
    gload_lds16(G + (size_t)(base + rowA1) * K + k0 + cb1, &sbuf[(256 + w * 64) * 8]);
  };

  stage(A,  sA[0], m0, 0);
  stage(BT, sB[0], n0, 0);
  __syncthreads();
  int cur = 0;
  for (int k0 = 0; k0 < K; k0 += 32) {
    const int nk = k0 + 32;
    if (nk < K) { stage(A, sA[cur ^ 1], m0, nk); stage(BT, sB[cur ^ 1], n0, nk); }
    half8 af[4], bf[4];
    #pragma unroll
    for (int m = 0; m < 4; ++m)
      af[m] = *(const half8*)&sA[cur][(wr * 64 + m * 16 + l15) * 32 + lhi * 8];
    #pragma unroll
    for (int n = 0; n < 4; ++n)
      bf[n] = *(const half8*)&sB[cur][(wc * 64 + n * 16 + l15) * 32 + lhi * 8];
    #pragma unroll
    for (int m = 0; m < 4; ++m)
      #pragma unroll
      for (int n = 0; n < 4; ++n)
        acc[m][n] = __builtin_amdgcn_mfma_f32_16x16x32_f16(af[m], bf[n], acc[m][n], 0, 0, 0);
    __syncthreads();
    cur ^= 1;
  }
  #pragma unroll
  for (int m = 0; m < 4; ++m) {
    const int row = m0 + wr * 64 + m * 16 + lhi * 4;
    #pragma unroll
    for (int n = 0; n < 4; ++n) {
      const int col = n0 + wc * 64 + n * 16 + l15;
      #pragma unroll
      for (int r = 0; r < 4; ++r)
        C[(size_t)(row + r) * N + col] = (OutT)acc[m][n][r];
    }
  }
}

// ---------------- fused attention v3: LDS-staged K/V, dbuf, XCD-local grid ----
// Flat grid 2048: id = tb*128 + (b*16+h) so the 16 blocks sharing (b,h) land on
// the same XCD (ids congruent mod 8) -> K/V L2-resident.
// Per chunk (64 s-rows): K chunk + V^T chunk staged to LDS by all 4 waves via
// global_load_lds(16B) with inverse-XOR-swizzled global source (LDS linear);
// ds_read_b128 at QK/PV applies the same XOR -> bank-conflict-free.
// Double-buffered; one __syncthreads per chunk (compiler adds vmcnt drain).
__global__ __launch_bounds__(256, 4) void attn_kernel(
    const _Float16* __restrict__ q, const _Float16* __restrict__ kv,
    const _Float16* __restrict__ vt, _Float16* __restrict__ ao)
{
  __shared__ __align__(16) _Float16 Ks[2][64 * 64];   // 8 KB each
  __shared__ __align__(16) _Float16 Vs[2][64 * 64];   // 8 KB each
  __shared__ __align__(16) _Float16 P[4][16][64];     // 8 KB
  const int tid = threadIdx.x;
  const int lane = tid & 63, w = tid >> 6;
  const int l15 = lane & 15, lhi = lane >> 4;
  const int id = blockIdx.x;
  const int bh = id & 127, tb = id >> 7;
  const int b = bh >> 4, h = bh & 15;
  const int t0 = tb * 64 + w * 16;

  const _Float16* qp = q + (size_t)(b * TT + t0 + l15) * HID + h * DH + lhi * 8;
  half8 aq0 = *(const half8*)qp;
  half8 aq1 = *(const half8*)(qp + 32);

  // staging geometry: per wave 2 instrs per buffer; instr (w*2+i) covers rows
  // (w*2+i)*8 + lane/8, 16B-chunk (lane&7), with source chunk XOR'd by row&7.
  const int srow = (lane >> 3);          // row offset within 8-row group
  const int sj   = (lane & 7) ^ srow;    // swizzled source 16B-chunk
  const _Float16* kbase = kv + (size_t)(b * S_) * 2048 + h * DH;
  const _Float16* vbase = vt + (size_t)((b * H_ + h) * DH) * S_;

  auto stageK = [&](int c, int pg) {
    #pragma unroll
    for (int i = 0; i < 2; ++i) {
      const int r = (w * 2 + i) * 8 + srow;
      gload_lds16(kbase + (size_t)(c * 64 + r) * 2048 + sj * 8,
                  &Ks[pg][(w * 2 + i) * 512]);
    }
  };
  auto stageV = [&](int c, int pg) {
    #pragma unroll
    for (int i = 0; i < 2; ++i) {
      const int r = (w * 2 + i) * 8 + srow;   // d-row of V^T
      gload_lds16(vbase + (size_t)r * S_ + c * 64 + sj * 8,
                  &Vs[pg][(w * 2 + i) * 512]);
    }
  };

  f32x4 acco[4] = {};
  float m_[4] = {-1e30f, -1e30f, -1e30f, -1e30f};
  float l_[4] = {0.f, 0.f, 0.f, 0.f};

  const int key = l15 & 7;
  const int ck0 = lhi ^ key;          // swizzled chunk for k-halfs [lhi*8,+8)
  const int swr = (l15 & 7) << 3;

  stageK(0, 0); stageV(0, 0);
  __syncthreads();
  int cur = 0;
  for (int c = 0; c < 8; ++c) {
    if (c + 1 < 8) { stageK(c + 1, cur ^ 1); stageV(c + 1, cur ^ 1); }
    // --- QK^T for 64 s-rows from LDS ---
    f32x4 accs[4] = {};
    #pragma unroll
    for (int n = 0; n < 4; ++n) {
      const int row = n * 16 + l15;
      half8 kf0 = *(const half8*)&Ks[cur][row * 64 + ck0 * 8];
      half8 kf1 = *(const half8*)&Ks[cur][row * 64 + (ck0 ^ 4) * 8];
      accs[n] = __builtin_amdgcn_mfma_f32_16x16x32_f16(aq0, kf0, accs[n], 0, 0, 0);
      accs[n] = __builtin_amdgcn_mfma_f32_16x16x32_f16(aq1, kf1, accs[n], 0, 0, 0);
    }
    // --- online softmax update (rows lhi*4+r, cols n*16+l15) ---
    #pragma unroll
    for (int r = 0; r < 4; ++r) {
      float mx = fmaxf(fmaxf(accs[0][r], accs[1][r]), fmaxf(accs[2][r], accs[3][r]));
      mx = fmaxf(mx, __shfl_xor(mx, 1, 64));
      mx = fmaxf(mx, __shfl_xor(mx, 2, 64));
      mx = fmaxf(mx, __shfl_xor(mx, 4, 64));
      mx = fmaxf(mx, __shfl_xor(mx, 8, 64));
      const float mnew = fmaxf(m_[r], mx);
      const float scale = __expf(m_[r] - mnew);
      float sm = 0.f;
      #pragma unroll
      for (int n = 0; n < 4; ++n) {
        float e = __expf(accs[n][r] - mnew);
        accs[n][r] = e;
        sm += e;
      }
      sm += __shfl_xor(sm, 1, 64);
      sm += __shfl_xor(sm, 2, 64);
      sm += __shfl_xor(sm, 4, 64);
      sm += __shfl_xor(sm, 8, 64);
      l_[r] = l_[r] * scale + sm;
      m_[r] = mnew;
      #pragma unroll
      for (int n2 = 0; n2 < 4; ++n2) acco[n2][r] *= scale;
      const int rw = lhi * 4 + r;
      const int sw = (rw & 7) << 3;
      #pragma unroll
      for (int n = 0; n < 4; ++n)
        P[w][rw][(n * 16 + l15) ^ sw] = (_Float16)accs[n][r];
    }
    // --- PV partial from LDS V^T chunk ---
    #pragma unroll
    for (int ks = 0; ks < 2; ++ks) {
      half8 ap = *(const half8*)&P[w][l15][(ks * 32 + lhi * 8) ^ swr];
      #pragma unroll
      for (int n = 0; n < 4; ++n) {
        const int row = n * 16 + l15;
        half8 vf = *(const half8*)&Vs[cur][row * 64 + ((ks * 4 + lhi) ^ key) * 8];
        acco[n] = __builtin_amdgcn_mfma_f32_16x16x32_f16(ap, vf, acco[n], 0, 0, 0);
      }
    }
    __syncthreads();
    cur ^= 1;
  }
  // --- finalize: /(sum * SCALE) and store ---
  _Float16* ob = ao + (size_t)(b * TT + t0 + lhi * 4) * HID + h * DH;
  #pragma unroll
  for (int r = 0; r < 4; ++r) {
    const float inv = 1.0f / (l_[r] * 8.0f);
    #pragma unroll
    for (int n = 0; n < 4; ++n)
      ob[(size_t)r * HID + n * 16 + l15] = (_Float16)(acco[n][r] * inv);
  }
}

extern "C" void kernel_launch(void* const* d_in, const int* in_sizes, int n_in,
                              void* d_out, int out_size, void* d_ws, size_t ws_size,
                              hipStream_t stream) {
  const float* x     = (const float*)d_in[0];
  const float* media = (const float*)d_in[1];
  // d_in[2] media_locations: unused (reference discards the mask)
  const float* Wq    = (const float*)d_in[3];
  const float* Wkv   = (const float*)d_in[4];
  const float* Wo    = (const float*)d_in[5];
  const float* gamma = (const float*)d_in[6];
  const float* beta  = (const float*)d_in[7];
  float* out = (float*)d_out;

  char* ws = (char*)d_ws;
  _Float16* xn     = (_Float16*)(ws);                    // 8192x2048 (32MB)
  _Float16* qh     = (_Float16*)(ws + 33554432);         // 8192x1024 (16MB)
  _Float16* kvh    = (_Float16*)(ws + 50331648);         // 4096x2048 (16MB)
  _Float16* aoh    = (_Float16*)(ws + 67108864);         // 8192x1024 (16MB)
  _Float16* vth    = (_Float16*)(ws + 83886080);         // 8x16x64x512 (8MB)
  _Float16* mediah = (_Float16*)(ws + 92274688);         // 4096x1024 (8MB)
  _Float16* wqT    = (_Float16*)(ws + 100663296);        // 1024x2048 (4MB)
  _Float16* wkvT   = (_Float16*)(ws + 104857600);        // 2048x1024 (4MB)
  _Float16* woT    = (_Float16*)(ws + 109051904);        // 2048x1024 (4MB)

  ln_cast<<<dim3(8192), dim3(256), 0, stream>>>(x, gamma, beta, xn);
  transpose_cast<<<dim3(1024/32, 2048/32), dim3(32, 8), 0, stream>>>(Wq,  wqT,  2048, 1024);
  transpose_cast<<<dim3(2048/32, 1024/32), dim3(32, 8), 0, stream>>>(Wkv, wkvT, 1024, 2048);
  transpose_cast<<<dim3(2048/32, 1024/32), dim3(32, 8), 0, stream>>>(Wo,  woT,  1024, 2048);
  cast_f16<<<dim3(4096), dim3(256), 0, stream>>>(media, mediah, 4194304 / 4);

  gemm_f16<_Float16><<<dim3(1024/128, 8192/128), dim3(256), 0, stream>>>(xn, wqT, qh, 8192, 1024, 2048);
  gemm_f16<_Float16><<<dim3(2048/128, 4096/128), dim3(256), 0, stream>>>(mediah, wkvT, kvh, 4096, 2048, 1024);
  build_vt<<<dim3(8, 16, 8), dim3(64, 8), 0, stream>>>(kvh, vth);
  attn_kernel<<<dim3(2048), dim3(256), 0, stream>>>(qh, kvh, vth, aoh);
  gemm_f16<float><<<dim3(2048/128, 8192/128), dim3(256), 0, stream>>>(aoh, woT, out, 8192, 2048, 1024);
}